// Round 6
// baseline (435.559 us; speedup 1.0000x reference)
//
#include <hip/hip_runtime.h>

typedef unsigned int u32;
typedef unsigned short u16;
typedef __attribute__((ext_vector_type(8))) short bf16x8;
typedef __attribute__((ext_vector_type(4))) float f32x4;

#define BB 2
#define SS 4096
#define NN 16
#define HH 64
#define GSZ 128
#define QT 128         // queries per block (8 waves x 16)
#define KT 64          // keys per tile
#define PITCH 70       // LDS row pitch in u16 (140B = 35 dw == 3 banks/row: <=2-way)
#define SCALE 0.125f

__device__ __forceinline__ u16 f2bf(float f){
    u32 x = __float_as_uint(f);
    return (u16)((x + 0x7fffu + ((x >> 16) & 1u)) >> 16);   // RNE
}
__device__ __forceinline__ u32 pk2(float a, float b){
    return (u32)f2bf(a) | ((u32)f2bf(b) << 16);
}

// ---- prep: convert K,V,GK,GV f32 -> bf16 into workspace (memory-bound) ----
__global__ __launch_bounds__(256) void prep_bf16(
    const float* __restrict__ K, const float* __restrict__ V,
    const float* __restrict__ GK, const float* __restrict__ GV,
    u16* __restrict__ ws, size_t NK, size_t NG)
{
    size_t idx = ((size_t)blockIdx.x * 256 + threadIdx.x) * 8;
    const float* src;
    if      (idx < NK)          src = K  + idx;
    else if (idx < 2*NK)        src = V  + (idx - NK);
    else if (idx < 2*NK + NG)   src = GK + (idx - 2*NK);
    else                        src = GV + (idx - 2*NK - NG);
    float4 a = *(const float4*)src;
    float4 b = *(const float4*)(src + 4);
    uint4 o = make_uint4(pk2(a.x,a.y), pk2(a.z,a.w), pk2(b.x,b.y), pk2(b.z,b.w));
    *(uint4*)(ws + idx) = o;
}

// PRE=1: K/V/GK/GV read as prestaged bf16; PRE=0: f32 + in-kernel convert.
template<int PRE>
__global__ __launch_bounds__(512, 4) void mmattn_mfma(
    const void* __restrict__ modal_index, int nseg,
    const float* __restrict__ Q,  const float* __restrict__ Kf, const float* __restrict__ Vf,
    const float* __restrict__ LM, const int* __restrict__ hasg_p,
    const float* __restrict__ GKf, const float* __restrict__ GVf, const float* __restrict__ GM,
    const u16* __restrict__ Kb, const u16* __restrict__ Vb,
    const u16* __restrict__ GKb, const u16* __restrict__ GVb,
    float* __restrict__ Out)
{
    __shared__ u16 Klds[KT * PITCH];        // [key][h]
    __shared__ u16 Vt  [HH * PITCH];        // [h][key]
    __shared__ u16 Pl  [8 * 16 * PITCH];    // per-wave [qrow][key]

    // ---- XCD-aware decode: blocks bid%8 -> XCD; give each XCD 4 (b,n) pairs ----
    const int bid = blockIdx.x;             // 0..1023
    const int xcd = bid & 7, ii = bid >> 3; // ii 0..127
    const int p   = xcd * 4 + (ii >> 5);    // (b,n) pair 0..31
    const int b   = p >> 4, n = p & 15;
    const int q0  = (ii & 31) * QT;

    const int tid = threadIdx.x;
    const int wid = tid >> 6, lane = tid & 63;
    const int lr  = lane & 15, lg = lane >> 4;
    const int srow = tid >> 3;              // staging key/row 0..63
    const int sc8  = (tid & 7) * 8;         // staging col (u16 units)

    // ---- segment lookup (int32 or int64 modal_index) ----
    const int*       p32 = (const int*)modal_index;
    const long long* p64 = (const long long*)modal_index;
    const bool is32 = (p32[2 * nseg - 1] == SS);
    int st = 0, en = SS;
    for (int i = 0; i < nseg; ++i) {
        int a = is32 ? p32[2*i]   : (int)p64[2*i];
        int c = is32 ? p32[2*i+1] : (int)p64[2*i+1];
        if (q0 >= a && q0 < c) { st = a; en = c; }
    }

    // ---- Q fragment (A-layout: row=lr, k = chunk*32 + lg*8 + i) ----
    bf16x8 qa0, qa1;
    {
        const float* qp = Q + (((size_t)(b * SS + q0 + wid * 16 + lr)) * NN + n) * HH + lg * 8;
        float4 f0 = *(const float4*)(qp);
        float4 f1 = *(const float4*)(qp + 4);
        float4 f2 = *(const float4*)(qp + 32);
        float4 f3 = *(const float4*)(qp + 36);
        union { u32 w[4]; bf16x8 v; } ua, ub;
        ua.w[0]=pk2(f0.x,f0.y); ua.w[1]=pk2(f0.z,f0.w); ua.w[2]=pk2(f1.x,f1.y); ua.w[3]=pk2(f1.z,f1.w);
        ub.w[0]=pk2(f2.x,f2.y); ub.w[1]=pk2(f2.z,f2.w); ub.w[2]=pk2(f3.x,f3.y); ub.w[3]=pk2(f3.z,f3.w);
        qa0 = ua.v; qa1 = ub.v;
    }

    f32x4 o[4];
    #pragma unroll
    for (int hb = 0; hb < 4; ++hb) { o[hb][0]=0.f; o[hb][1]=0.f; o[hb][2]=0.f; o[hb][3]=0.f; }
    float m[4] = {-1e30f,-1e30f,-1e30f,-1e30f};
    float l[4] = {0.f,0.f,0.f,0.f};

    u16* Plw = &Pl[wid * 16 * PITCH];

    // kb/vb: element base of 64-row tile; rs: row stride in elements (same count for f32/bf16)
    auto tile = [&](const void* kb, const void* vb, size_t rs, const float* mp) {
        if constexpr (PRE) {
            const u16* kp = (const u16*)kb + (size_t)srow * rs + sc8;
            *(uint4*)&Klds[srow * PITCH + sc8] = *(const uint4*)kp;
            const u16* vp = (const u16*)vb + (size_t)srow * rs + sc8;
            uint4 w = *(const uint4*)vp;
            u16 vv[8] = {(u16)w.x,(u16)(w.x>>16),(u16)w.y,(u16)(w.y>>16),
                         (u16)w.z,(u16)(w.z>>16),(u16)w.w,(u16)(w.w>>16)};
            #pragma unroll
            for (int j = 0; j < 8; ++j) Vt[(sc8 + j) * PITCH + srow] = vv[j];
        } else {
            const float* kp = (const float*)kb + (size_t)srow * rs + sc8;
            float4 ka = *(const float4*)kp;
            float4 kc = *(const float4*)(kp + 4);
            *(uint4*)&Klds[srow * PITCH + sc8] =
                make_uint4(pk2(ka.x,ka.y), pk2(ka.z,ka.w), pk2(kc.x,kc.y), pk2(kc.z,kc.w));
            const float* vp = (const float*)vb + (size_t)srow * rs + sc8;
            float4 va = *(const float4*)vp;
            float4 vc = *(const float4*)(vp + 4);
            float vv[8] = {va.x,va.y,va.z,va.w, vc.x,vc.y,vc.z,vc.w};
            #pragma unroll
            for (int j = 0; j < 8; ++j) Vt[(sc8 + j) * PITCH + srow] = f2bf(vv[j]);
        }
        __syncthreads();

        float mk[4];
        #pragma unroll
        for (int cb = 0; cb < 4; ++cb) mk[cb] = mp[cb * 16 + lr];

        // ---- QK^T ----
        f32x4 s[4];
        #pragma unroll
        for (int cb = 0; cb < 4; ++cb) {
            const bf16x8 kb0 = *(const bf16x8*)&Klds[(cb*16 + lr) * PITCH + lg*8];
            const bf16x8 kb1 = *(const bf16x8*)&Klds[(cb*16 + lr) * PITCH + 32 + lg*8];
            f32x4 acc; acc[0]=0.f; acc[1]=0.f; acc[2]=0.f; acc[3]=0.f;
            acc = __builtin_amdgcn_mfma_f32_16x16x32_bf16(qa0, kb0, acc, 0, 0, 0);
            acc = __builtin_amdgcn_mfma_f32_16x16x32_bf16(qa1, kb1, acc, 0, 0, 0);
            s[cb] = acc;
        }

        // ---- online softmax per D-row, P -> wave-local LDS ----
        float cr[4];
        #pragma unroll
        for (int r = 0; r < 4; ++r) {
            float s0 = s[0][r]*SCALE + mk[0];
            float s1 = s[1][r]*SCALE + mk[1];
            float s2 = s[2][r]*SCALE + mk[2];
            float s3 = s[3][r]*SCALE + mk[3];
            float mx = fmaxf(fmaxf(s0, s1), fmaxf(s2, s3));
            mx = fmaxf(mx, __shfl_xor(mx, 1));
            mx = fmaxf(mx, __shfl_xor(mx, 2));
            mx = fmaxf(mx, __shfl_xor(mx, 4));
            mx = fmaxf(mx, __shfl_xor(mx, 8));
            float nm = fmaxf(m[r], mx);
            float c_ = __expf(m[r] - nm);
            m[r] = nm;
            float p0 = __expf(s0 - nm), p1 = __expf(s1 - nm);
            float p2 = __expf(s2 - nm), p3 = __expf(s3 - nm);
            float rsum = (p0 + p1) + (p2 + p3);
            rsum += __shfl_xor(rsum, 1);
            rsum += __shfl_xor(rsum, 2);
            rsum += __shfl_xor(rsum, 4);
            rsum += __shfl_xor(rsum, 8);
            l[r] = l[r] * c_ + rsum;
            cr[r] = c_;
            u16* pw = &Plw[(lg * 4 + r) * PITCH + lr];
            pw[0]  = f2bf(p0); pw[16] = f2bf(p1);
            pw[32] = f2bf(p2); pw[48] = f2bf(p3);
        }
        #pragma unroll
        for (int hb = 0; hb < 4; ++hb) {
            o[hb][0]*=cr[0]; o[hb][1]*=cr[1]; o[hb][2]*=cr[2]; o[hb][3]*=cr[3];
        }

        // ---- PV ----
        const bf16x8 pa0 = *(const bf16x8*)&Plw[lr * PITCH + lg*8];
        const bf16x8 pa1 = *(const bf16x8*)&Plw[lr * PITCH + 32 + lg*8];
        #pragma unroll
        for (int hb = 0; hb < 4; ++hb) {
            const bf16x8 vb0 = *(const bf16x8*)&Vt[(hb*16 + lr) * PITCH + lg*8];
            const bf16x8 vb1 = *(const bf16x8*)&Vt[(hb*16 + lr) * PITCH + 32 + lg*8];
            o[hb] = __builtin_amdgcn_mfma_f32_16x16x32_bf16(pa0, vb0, o[hb], 0, 0, 0);
            o[hb] = __builtin_amdgcn_mfma_f32_16x16x32_bf16(pa1, vb1, o[hb], 0, 0, 0);
        }
        __syncthreads();
    };

    // ---- global key tiles ----
    if (*hasg_p) {
        const float* gmb = GM + (size_t)b * GSZ;
        if constexpr (PRE) {
            const u16* gkb = GKb + ((size_t)(b * NN + n)) * GSZ * HH;
            const u16* gvb = GVb + ((size_t)(b * NN + n)) * GSZ * HH;
            tile(gkb,           gvb,           HH, gmb);
            tile(gkb + 64*HH,   gvb + 64*HH,   HH, gmb + 64);
        } else {
            const float* gkb = GKf + ((size_t)(b * NN + n)) * GSZ * HH;
            const float* gvb = GVf + ((size_t)(b * NN + n)) * GSZ * HH;
            tile(gkb,           gvb,           HH, gmb);
            tile(gkb + 64*HH,   gvb + 64*HH,   HH, gmb + 64);
        }
    }
    // ---- local segment tiles ----
    {
        const float* lmb = LM + (size_t)b * SS;
        for (int k0 = st; k0 < en; k0 += KT) {
            if constexpr (PRE) {
                tile(Kb + (((size_t)(b * SS + k0)) * NN + n) * HH,
                     Vb + (((size_t)(b * SS + k0)) * NN + n) * HH,
                     (size_t)NN * HH, lmb + k0);
            } else {
                tile(Kf + (((size_t)(b * SS + k0)) * NN + n) * HH,
                     Vf + (((size_t)(b * SS + k0)) * NN + n) * HH,
                     (size_t)NN * HH, lmb + k0);
            }
        }
    }

    // ---- epilogue ----
    float inv[4] = {1.f/l[0], 1.f/l[1], 1.f/l[2], 1.f/l[3]};
    #pragma unroll
    for (int hb = 0; hb < 4; ++hb) {
        #pragma unroll
        for (int r = 0; r < 4; ++r) {
            const int qrow = q0 + wid * 16 + lg * 4 + r;
            Out[(((size_t)(b * SS + qrow)) * NN + n) * HH + hb * 16 + lr] = o[hb][r] * inv[r];
        }
    }
}

extern "C" void kernel_launch(void* const* d_in, const int* in_sizes, int n_in,
                              void* d_out, int out_size, void* d_ws, size_t ws_size,
                              hipStream_t stream)
{
    const void* modal = d_in[0];
    const int   nseg  = in_sizes[0] / 2;
    const float* Q  = (const float*)d_in[1];
    const float* K  = (const float*)d_in[2];
    const float* V  = (const float*)d_in[3];
    const float* LM = (const float*)d_in[4];
    const int*   HG = (const int*)d_in[5];
    const float* GK = (const float*)d_in[6];
    const float* GV = (const float*)d_in[7];
    const float* GM = (const float*)d_in[8];
    float* Out = (float*)d_out;

    const size_t NK = (size_t)BB * SS * NN * HH;    // 8,388,608
    const size_t NG = (size_t)BB * NN * GSZ * HH;   //   262,144
    const size_t need = (2*NK + 2*NG) * sizeof(u16);

    const int nblk = (SS / QT) * NN * BB;           // 1024

    if (d_ws && ws_size >= need) {
        u16* wsp = (u16*)d_ws;
        const size_t tot8 = (2*NK + 2*NG) / 8;      // threads for prep
        prep_bf16<<<(int)(tot8 / 256), 256, 0, stream>>>(K, V, GK, GV, wsp, NK, NG);
        mmattn_mfma<1><<<nblk, 512, 0, stream>>>(modal, nseg, Q, K, V, LM, HG, GK, GV, GM,
                                                 wsp, wsp + NK, wsp + 2*NK, wsp + 2*NK + NG, Out);
    } else {
        mmattn_mfma<0><<<nblk, 512, 0, stream>>>(modal, nseg, Q, K, V, LM, HG, GK, GV, GM,
                                                 nullptr, nullptr, nullptr, nullptr, Out);
    }
}

// Round 7
// 359.524 us; speedup vs baseline: 1.2115x; 1.2115x over previous
//
#include <hip/hip_runtime.h>

typedef unsigned int u32;
typedef unsigned short u16;
typedef __attribute__((ext_vector_type(8))) short bf16x8;
typedef __attribute__((ext_vector_type(4))) float f32x4;

#define BB 2
#define SS 4096
#define NN 16
#define HH 64
#define GSZ 128
#define QT 64          // queries per block (4 waves x 16)
#define KT 64          // keys per tile
#define PITCH 70       // LDS row pitch in u16 (validated round 6: b128 @ 8B-align OK)
#define SCALE 0.125f
#define THR 8.0f       // defer-max threshold (P bounded by e^8)

__device__ __forceinline__ u16 f2bf(float f){
    u32 x = __float_as_uint(f);
    return (u16)((x + 0x7fffu + ((x >> 16) & 1u)) >> 16);   // RNE
}
__device__ __forceinline__ u32 pk2(float a, float b){
    return (u32)f2bf(a) | ((u32)f2bf(b) << 16);
}

// ---- prep: convert K,V,GK,GV f32 -> bf16 into workspace ----
__global__ __launch_bounds__(256) void prep_bf16(
    const float* __restrict__ K, const float* __restrict__ V,
    const float* __restrict__ GK, const float* __restrict__ GV,
    u16* __restrict__ ws, size_t NK, size_t NG)
{
    size_t idx = ((size_t)blockIdx.x * 256 + threadIdx.x) * 8;
    const float* src;
    if      (idx < NK)          src = K  + idx;
    else if (idx < 2*NK)        src = V  + (idx - NK);
    else if (idx < 2*NK + NG)   src = GK + (idx - 2*NK);
    else                        src = GV + (idx - 2*NK - NG);
    float4 a = *(const float4*)src;
    float4 b = *(const float4*)(src + 4);
    *(uint4*)(ws + idx) = make_uint4(pk2(a.x,a.y), pk2(a.z,a.w), pk2(b.x,b.y), pk2(b.z,b.w));
}

template<int PRE>
__global__ __launch_bounds__(256, 3) void mmattn_mfma(
    const void* __restrict__ modal_index, int nseg,
    const float* __restrict__ Q,  const float* __restrict__ Kf, const float* __restrict__ Vf,
    const float* __restrict__ LM, const int* __restrict__ hasg_p,
    const float* __restrict__ GKf, const float* __restrict__ GVf, const float* __restrict__ GM,
    const u16* __restrict__ Kb, const u16* __restrict__ Vb,
    const u16* __restrict__ GKb, const u16* __restrict__ GVb,
    float* __restrict__ Out)
{
    __shared__ u16 Kl[2][KT * PITCH];       // [buf][key][h]
    __shared__ u16 Vt[2][HH * PITCH];       // [buf][h][key]
    __shared__ u16 Pl[4 * 16 * PITCH];      // per-wave [qrow][key]

    // XCD-aware decode: 2048 blocks; each XCD owns 4 (b,n) pairs
    const int bid = blockIdx.x;
    const int xcd = bid & 7, ii = bid >> 3;     // ii 0..255
    const int pr  = xcd * 4 + (ii >> 6);        // (b,n) pair 0..31
    const int b   = pr >> 4, n = pr & 15;
    const int q0  = (ii & 63) * QT;

    const int tid = threadIdx.x;
    const int wid = tid >> 6, lane = tid & 63;
    const int lr  = lane & 15, lg = lane >> 4;
    const int rp  = tid >> 3;                   // staging row-pair 0..31
    const int g8  = (tid & 7) * 8;              // staging col start (u16)

    // ---- segment lookup (int32 or int64 modal_index) ----
    const int*       p32 = (const int*)modal_index;
    const long long* p64 = (const long long*)modal_index;
    const bool is32 = (p32[2 * nseg - 1] == SS);
    int st = 0, en = SS;
    for (int i = 0; i < nseg; ++i) {
        int a = is32 ? p32[2*i]   : (int)p64[2*i];
        int c = is32 ? p32[2*i+1] : (int)p64[2*i+1];
        if (q0 >= a && q0 < c) { st = a; en = c; }
    }
    const int ng = (*hasg_p) ? 2 : 0;
    const int nt = ng + (en - st) / KT;

    // ---- Q fragment (A-layout: row=lr, k = chunk*32 + lg*8 + i) ----
    bf16x8 qa0, qa1;
    {
        const float* qp = Q + (((size_t)(b * SS + q0 + wid * 16 + lr)) * NN + n) * HH + lg * 8;
        float4 f0 = *(const float4*)(qp);
        float4 f1 = *(const float4*)(qp + 4);
        float4 f2 = *(const float4*)(qp + 32);
        float4 f3 = *(const float4*)(qp + 36);
        union { u32 w[4]; bf16x8 v; } ua, ub;
        ua.w[0]=pk2(f0.x,f0.y); ua.w[1]=pk2(f0.z,f0.w); ua.w[2]=pk2(f1.x,f1.y); ua.w[3]=pk2(f1.z,f1.w);
        ub.w[0]=pk2(f2.x,f2.y); ub.w[1]=pk2(f2.z,f2.w); ub.w[2]=pk2(f3.x,f3.y); ub.w[3]=pk2(f3.z,f3.w);
        qa0 = ua.v; qa1 = ub.v;
    }

    f32x4 o[4];
    #pragma unroll
    for (int hb = 0; hb < 4; ++hb) { o[hb][0]=0.f; o[hb][1]=0.f; o[hb][2]=0.f; o[hb][3]=0.f; }
    float m[4] = {-1e30f,-1e30f,-1e30f,-1e30f};
    float l[4] = {0.f,0.f,0.f,0.f};
    u16* Plw = &Pl[wid * 16 * PITCH];

    auto ptrs = [&](int t, const void*& kp, const void*& vp, size_t& rs, const float*& mp) {
        if (t < ng) {
            size_t off = ((size_t)(b * NN + n)) * GSZ * HH + (size_t)t * KT * HH;
            if constexpr (PRE) { kp = GKb + off; vp = GVb + off; }
            else               { kp = GKf + off; vp = GVf + off; }
            rs = HH; mp = GM + (size_t)b * GSZ + t * KT;
        } else {
            int k0 = st + (t - ng) * KT;
            size_t off = (((size_t)(b * SS + k0)) * NN + n) * HH;
            if constexpr (PRE) { kp = Kb + off; vp = Vb + off; }
            else               { kp = Kf + off; vp = Vf + off; }
            rs = (size_t)NN * HH; mp = LM + (size_t)b * SS + k0;
        }
    };

    // staging registers (held across compute for async split)
    uint4 kr0, kr1, vr0, vr1;                                   // PRE=1
    float4 ka0,ka1,kb0_,kb1_, va0,va1,vb0_,vb1_;                // PRE=0

    auto issue = [&](int t) {
        const void *kp, *vp; size_t rs; const float* mp_;
        ptrs(t, kp, vp, rs, mp_);
        if constexpr (PRE) {
            const u16* k0p = (const u16*)kp + (size_t)(2*rp)   * rs + g8;
            const u16* k1p = (const u16*)kp + (size_t)(2*rp+1) * rs + g8;
            const u16* v0p = (const u16*)vp + (size_t)(2*rp)   * rs + g8;
            const u16* v1p = (const u16*)vp + (size_t)(2*rp+1) * rs + g8;
            kr0 = *(const uint4*)k0p; kr1 = *(const uint4*)k1p;
            vr0 = *(const uint4*)v0p; vr1 = *(const uint4*)v1p;
        } else {
            const float* k0p = (const float*)kp + (size_t)(2*rp)   * rs + g8;
            const float* k1p = (const float*)kp + (size_t)(2*rp+1) * rs + g8;
            const float* v0p = (const float*)vp + (size_t)(2*rp)   * rs + g8;
            const float* v1p = (const float*)vp + (size_t)(2*rp+1) * rs + g8;
            ka0 = *(const float4*)k0p; ka1 = *(const float4*)(k0p + 4);
            kb0_= *(const float4*)k1p; kb1_= *(const float4*)(k1p + 4);
            va0 = *(const float4*)v0p; va1 = *(const float4*)(v0p + 4);
            vb0_= *(const float4*)v1p; vb1_= *(const float4*)(v1p + 4);
        }
    };

    auto commit = [&](int bi) {
        if constexpr (PRE) {
            *(uint4*)&Kl[bi][(2*rp)   * PITCH + g8] = kr0;
            *(uint4*)&Kl[bi][(2*rp+1) * PITCH + g8] = kr1;
            union { uint4 v; u16 h[8]; } a, c;
            a.v = vr0; c.v = vr1;
            #pragma unroll
            for (int j = 0; j < 8; ++j) {
                u32 w = (u32)a.h[j] | ((u32)c.h[j] << 16);
                *(u32*)&Vt[bi][(g8 + j) * PITCH + 2*rp] = w;   // 2-way max: free
            }
        } else {
            *(uint4*)&Kl[bi][(2*rp)   * PITCH + g8] =
                make_uint4(pk2(ka0.x,ka0.y), pk2(ka0.z,ka0.w), pk2(ka1.x,ka1.y), pk2(ka1.z,ka1.w));
            *(uint4*)&Kl[bi][(2*rp+1) * PITCH + g8] =
                make_uint4(pk2(kb0_.x,kb0_.y), pk2(kb0_.z,kb0_.w), pk2(kb1_.x,kb1_.y), pk2(kb1_.z,kb1_.w));
            float va[8] = {va0.x,va0.y,va0.z,va0.w, va1.x,va1.y,va1.z,va1.w};
            float vc[8] = {vb0_.x,vb0_.y,vb0_.z,vb0_.w, vb1_.x,vb1_.y,vb1_.z,vb1_.w};
            #pragma unroll
            for (int j = 0; j < 8; ++j) {
                u32 w = (u32)f2bf(va[j]) | ((u32)f2bf(vc[j]) << 16);
                *(u32*)&Vt[bi][(g8 + j) * PITCH + 2*rp] = w;
            }
        }
    };

    // ---- pipelined main loop: one barrier per tile ----
    issue(0); commit(0); __syncthreads();
    int cur = 0;
    for (int t = 0; t < nt; ++t) {
        if (t + 1 < nt) issue(t + 1);          // async: loads fly under compute

        const void *kp_, *vp_; size_t rs_; const float* mp_;
        ptrs(t, kp_, vp_, rs_, mp_);
        float mk[4];
        #pragma unroll
        for (int cb = 0; cb < 4; ++cb) mk[cb] = mp_[cb * 16 + lr];

        // QK^T
        f32x4 s[4];
        #pragma unroll
        for (int cb = 0; cb < 4; ++cb) {
            const bf16x8 kf0 = *(const bf16x8*)&Kl[cur][(cb*16 + lr) * PITCH + lg*8];
            const bf16x8 kf1 = *(const bf16x8*)&Kl[cur][(cb*16 + lr) * PITCH + 32 + lg*8];
            f32x4 acc; acc[0]=0.f; acc[1]=0.f; acc[2]=0.f; acc[3]=0.f;
            acc = __builtin_amdgcn_mfma_f32_16x16x32_bf16(qa0, kf0, acc, 0, 0, 0);
            acc = __builtin_amdgcn_mfma_f32_16x16x32_bf16(qa1, kf1, acc, 0, 0, 0);
            s[cb] = acc;
        }

        // defer-max online softmax (fast path: no shuffles, no rescale)
        float sv[4][4], pm[4];
        #pragma unroll
        for (int r = 0; r < 4; ++r) {
            #pragma unroll
            for (int cb = 0; cb < 4; ++cb) sv[r][cb] = s[cb][r] * SCALE + mk[cb];
            pm[r] = fmaxf(fmaxf(sv[r][0], sv[r][1]), fmaxf(sv[r][2], sv[r][3]));
        }
        int lok = (pm[0] <= m[0] + THR) & (pm[1] <= m[1] + THR) &
                  (pm[2] <= m[2] + THR) & (pm[3] <= m[3] + THR);
        if (!__all(lok)) {                      // rare (always on tile 0)
            #pragma unroll
            for (int r = 0; r < 4; ++r) {
                float mx = pm[r];
                mx = fmaxf(mx, __shfl_xor(mx, 1));
                mx = fmaxf(mx, __shfl_xor(mx, 2));
                mx = fmaxf(mx, __shfl_xor(mx, 4));
                mx = fmaxf(mx, __shfl_xor(mx, 8));
                float nm = fmaxf(m[r], mx);
                float c_ = __expf(m[r] - nm);
                l[r] *= c_;
                o[0][r] *= c_; o[1][r] *= c_; o[2][r] *= c_; o[3][r] *= c_;
                m[r] = nm;
            }
        }
        #pragma unroll
        for (int r = 0; r < 4; ++r) {
            float p0 = __expf(sv[r][0] - m[r]);
            float p1 = __expf(sv[r][1] - m[r]);
            float p2 = __expf(sv[r][2] - m[r]);
            float p3 = __expf(sv[r][3] - m[r]);
            l[r] += (p0 + p1) + (p2 + p3);      // per-lane partial; reduced at end
            u16* pw = &Plw[(lg * 4 + r) * PITCH + lr];
            pw[0]  = f2bf(p0); pw[16] = f2bf(p1);
            pw[32] = f2bf(p2); pw[48] = f2bf(p3);
        }

        // PV
        const bf16x8 pa0 = *(const bf16x8*)&Plw[lr * PITCH + lg*8];
        const bf16x8 pa1 = *(const bf16x8*)&Plw[lr * PITCH + 32 + lg*8];
        #pragma unroll
        for (int hb = 0; hb < 4; ++hb) {
            const bf16x8 vf0 = *(const bf16x8*)&Vt[cur][(hb*16 + lr) * PITCH + lg*8];
            const bf16x8 vf1 = *(const bf16x8*)&Vt[cur][(hb*16 + lr) * PITCH + 32 + lg*8];
            o[hb] = __builtin_amdgcn_mfma_f32_16x16x32_bf16(pa0, vf0, o[hb], 0, 0, 0);
            o[hb] = __builtin_amdgcn_mfma_f32_16x16x32_bf16(pa1, vf1, o[hb], 0, 0, 0);
        }

        if (t + 1 < nt) commit(cur ^ 1);       // write other buffer (safe pre-barrier)
        __syncthreads();
        cur ^= 1;
    }

    // ---- epilogue: reduce l across the 16-lane row group, normalize, store ----
    #pragma unroll
    for (int r = 0; r < 4; ++r) {
        float t_ = l[r];
        t_ += __shfl_xor(t_, 1);
        t_ += __shfl_xor(t_, 2);
        t_ += __shfl_xor(t_, 4);
        t_ += __shfl_xor(t_, 8);
        l[r] = t_;
    }
    float inv[4] = {1.f/l[0], 1.f/l[1], 1.f/l[2], 1.f/l[3]};
    #pragma unroll
    for (int hb = 0; hb < 4; ++hb) {
        #pragma unroll
        for (int r = 0; r < 4; ++r) {
            const int qrow = q0 + wid * 16 + lg * 4 + r;
            Out[(((size_t)(b * SS + qrow)) * NN + n) * HH + hb * 16 + lr] = o[hb][r] * inv[r];
        }
    }
}

extern "C" void kernel_launch(void* const* d_in, const int* in_sizes, int n_in,
                              void* d_out, int out_size, void* d_ws, size_t ws_size,
                              hipStream_t stream)
{
    const void* modal = d_in[0];
    const int   nseg  = in_sizes[0] / 2;
    const float* Q  = (const float*)d_in[1];
    const float* K  = (const float*)d_in[2];
    const float* V  = (const float*)d_in[3];
    const float* LM = (const float*)d_in[4];
    const int*   HG = (const int*)d_in[5];
    const float* GK = (const float*)d_in[6];
    const float* GV = (const float*)d_in[7];
    const float* GM = (const float*)d_in[8];
    float* Out = (float*)d_out;

    const size_t NK = (size_t)BB * SS * NN * HH;    // 8,388,608
    const size_t NG = (size_t)BB * NN * GSZ * HH;   //   262,144
    const size_t need = (2*NK + 2*NG) * sizeof(u16);
    const int nblk = (SS / QT) * NN * BB;           // 2048

    if (d_ws && ws_size >= need) {
        u16* wsp = (u16*)d_ws;
        const size_t tot8 = (2*NK + 2*NG) / 8;
        prep_bf16<<<(int)(tot8 / 256), 256, 0, stream>>>(K, V, GK, GV, wsp, NK, NG);
        mmattn_mfma<1><<<nblk, 256, 0, stream>>>(modal, nseg, Q, K, V, LM, HG, GK, GV, GM,
                                                 wsp, wsp + NK, wsp + 2*NK, wsp + 2*NK + NG, Out);
    } else {
        mmattn_mfma<0><<<nblk, 256, 0, stream>>>(modal, nseg, Q, K, V, LM, HG, GK, GV, GM,
                                                 nullptr, nullptr, nullptr, nullptr, Out);
    }
}